// Round 6
// baseline (268.764 us; speedup 1.0000x reference)
//
#include <hip/hip_runtime.h>
#include <hip/hip_bf16.h>
#include <math.h>

#define DIM 64
#define GNUM 256
#define CNUM 10

// bf16x2 pack/unpack (RNE). h intermediates are bf16 for gather traffic;
// alpha/softmax math stays f32.
__device__ __forceinline__ unsigned bfpack(float a, float b) {
    unsigned ua = __builtin_bit_cast(unsigned, a);
    unsigned ub = __builtin_bit_cast(unsigned, b);
    ua += 0x7fffu + ((ua >> 16) & 1u);
    ub += 0x7fffu + ((ub >> 16) & 1u);
    return (ua >> 16) | (ub & 0xffff0000u);
}
__device__ __forceinline__ float bflo(unsigned u) { return __builtin_bit_cast(float, u << 16); }
__device__ __forceinline__ float bfhi(unsigned u) { return __builtin_bit_cast(float, u & 0xffff0000u); }

// ---------------- CSR build ----------------
__global__ void deg_rank_kernel(const int* __restrict__ ei, int E, int N,
                                int* __restrict__ deg, int* __restrict__ rank) {
    int i = blockIdx.x * blockDim.x + threadIdx.x;
    int EP = E + N;
    if (i >= EP) return;
    int d = (i < E) ? ei[E + i] : (i - E);   // row 1 of edge_index = dst; self loops appended
    rank[i] = atomicAdd(&deg[d], 1);
}

// scan_blocks + graph_bounds, role-split by blockIdx. (proven R12 version —
// R13's single-dispatch lookback scan was the prime hang suspect; reverted.)
__global__ __launch_bounds__(256) void scan_misc(const int* __restrict__ deg, int* __restrict__ part, int n, int nb,
                                                 const int* __restrict__ batch, int N,
                                                 int* __restrict__ gstart) {
    int bid = blockIdx.x;
    if (bid < nb) {
        __shared__ int ws[4];
        int i = bid * 256 + threadIdx.x;
        int v = (i < n) ? deg[i] : 0;
        #pragma unroll
        for (int d = 32; d >= 1; d >>= 1) v += __shfl_xor(v, d);
        if ((threadIdx.x & 63) == 0) ws[threadIdx.x >> 6] = v;
        __syncthreads();
        if (threadIdx.x == 0) part[bid] = ws[0] + ws[1] + ws[2] + ws[3];
    } else {
        for (int g = threadIdx.x; g <= GNUM; g += 256) {
            int lo = 0, hi = N;
            while (lo < hi) { int mid = (lo + hi) >> 1; if (batch[mid] < g) lo = mid + 1; else hi = mid; }
            gstart[g] = lo;
        }
    }
}

// scan_down with the top-level scan fused (nb <= 256 for N <= 65536).
__global__ __launch_bounds__(256) void scan_down(const int* __restrict__ deg, const int* __restrict__ part,
                                                 int* __restrict__ offs, int n) {
    __shared__ int ws[4];
    __shared__ int base_s;
    int tid = threadIdx.x, lane = tid & 63, wid = tid >> 6;
    int pv = (tid < (int)blockIdx.x) ? part[tid] : 0;
    #pragma unroll
    for (int d = 32; d >= 1; d >>= 1) pv += __shfl_xor(pv, d);
    if (lane == 0) ws[wid] = pv;
    __syncthreads();
    if (tid == 0) base_s = ws[0] + ws[1] + ws[2] + ws[3];
    __syncthreads();
    int i = blockIdx.x * 256 + tid;
    int v = (i < n) ? deg[i] : 0;
    int x = v;
    #pragma unroll
    for (int d = 1; d < 64; d <<= 1) { int t = __shfl_up(x, d); if (lane >= d) x += t; }
    if (lane == 63) ws[wid] = x;
    __syncthreads();
    int add = base_s;
    for (int w = 0; w < wid; ++w) add += ws[w];
    if (i < n) offs[i] = add + x - v;
    if (i == n - 1) offs[n] = add + x;
}

// ---------------- 512-thread 64x64 mm pieces ----------------
#define XSTR 68
__device__ __forceinline__ void mm_core_512(const float* __restrict__ xT, const float* __restrict__ Ws,
                                            const float* __restrict__ a_s, const float* __restrict__ a_d,
                                            unsigned* __restrict__ hbn, float* __restrict__ asn,
                                            float* __restrict__ adn, int base, int N) {
    int tid = threadIdx.x;
    int tx = tid & 15, ty = tid >> 4;          // ty 0..31
    int c0 = tx << 2, r0 = ty << 1;
    float acc[2][4] = {{0.f}};
    #pragma unroll 8
    for (int k = 0; k < DIM; ++k) {
        float2 xv = *(const float2*)(xT + k * XSTR + r0);
        float4 wv = *(const float4*)(Ws + k * DIM + c0);
        acc[0][0] += xv.x * wv.x; acc[0][1] += xv.x * wv.y; acc[0][2] += xv.x * wv.z; acc[0][3] += xv.x * wv.w;
        acc[1][0] += xv.y * wv.x; acc[1][1] += xv.y * wv.y; acc[1][2] += xv.y * wv.z; acc[1][3] += xv.y * wv.w;
    }
    float4 av = *(const float4*)(a_s + c0);
    float4 dv = *(const float4*)(a_d + c0);
    #pragma unroll
    for (int ri = 0; ri < 2; ++ri) {
        int grow = base + r0 + ri;
        float s1 = acc[ri][0] * av.x + acc[ri][1] * av.y + acc[ri][2] * av.z + acc[ri][3] * av.w;
        float s2 = acc[ri][0] * dv.x + acc[ri][1] * dv.y + acc[ri][2] * dv.z + acc[ri][3] * dv.w;
        #pragma unroll
        for (int d = 1; d <= 8; d <<= 1) { s1 += __shfl_xor(s1, d); s2 += __shfl_xor(s2, d); }
        if (grow < N) {
            uint2 o;
            o.x = bfpack(acc[ri][0], acc[ri][1]);
            o.y = bfpack(acc[ri][2], acc[ri][3]);
            *(uint2*)(hbn + ((size_t)grow << 5) + (tx << 1)) = o;
            if (tx == 0) { asn[grow] = s1; adn[grow] = s2; }
        }
    }
}

// layer-1 mm (f32 input, 512 threads) + atomic-free CSR scatter, role-split.
__global__ __launch_bounds__(512) void mm_fill(const float* __restrict__ in, const float* __restrict__ W,
                                               const float* __restrict__ a_s, const float* __restrict__ a_d,
                                               unsigned* __restrict__ hb, float* __restrict__ as_,
                                               float* __restrict__ ad_, int N, int nbt,
                                               const int* __restrict__ ei, const int* __restrict__ rank, int E,
                                               const int* __restrict__ offs, int2* __restrict__ csr_sd) {
    int bid = blockIdx.x;
    if (bid < nbt) {
        __shared__ float Ws[DIM * DIM];
        __shared__ float xT[XSTR * DIM];
        int tid = threadIdx.x;
        int base = bid * 64;

        const float4* W4 = (const float4*)W;
        float4* Ws4 = (float4*)Ws;
        Ws4[tid] = W4[tid];
        Ws4[tid + 512] = W4[tid + 512];

        {
            int row = tid >> 3;
            int kb = (tid & 7) << 3;
            int grow = base + row;
            int crow = grow < N ? grow : N - 1;
            const float4* xr = (const float4*)(in + ((size_t)crow << 6) + kb);
            float4 v0 = xr[0], v1 = xr[1];
            xT[(kb + 0) * XSTR + row] = v0.x;  xT[(kb + 1) * XSTR + row] = v0.y;
            xT[(kb + 2) * XSTR + row] = v0.z;  xT[(kb + 3) * XSTR + row] = v0.w;
            xT[(kb + 4) * XSTR + row] = v1.x;  xT[(kb + 5) * XSTR + row] = v1.y;
            xT[(kb + 6) * XSTR + row] = v1.z;  xT[(kb + 7) * XSTR + row] = v1.w;
        }
        __syncthreads();
        mm_core_512(xT, Ws, a_s, a_d, hb, as_, ad_, base, N);
    } else {
        int i = (bid - nbt) * 512 + threadIdx.x;
        int EP = E + N;
        if (i >= EP) return;
        int s, d;
        if (i < E) { s = ei[i]; d = ei[E + i]; } else { s = i - E; d = i - E; }
        csr_sd[offs[d] + rank[i]] = make_int2(s, d);
    }
}

// ---------------- fused agg(layer k) + mm(layer k+1), 512 threads ----------------
#define FUS_NPB 64
#define FUS_CAP 2560
__global__ __launch_bounds__(512) void agg_mm(const unsigned* __restrict__ hbp,
                                              const int2* __restrict__ csr_sd,
                                              const float* __restrict__ asp,
                                              const float* __restrict__ adp,
                                              const int* __restrict__ offs,
                                              const float* __restrict__ bias,
                                              const float* __restrict__ W,
                                              const float* __restrict__ a_s,
                                              const float* __restrict__ a_d,
                                              unsigned* __restrict__ hbn,
                                              float* __restrict__ asn,
                                              float* __restrict__ adn, int N) {
    __shared__ int soffs[FUS_NPB + 1];
    __shared__ float adl[FUS_NPB];
    __shared__ int2 lsw[FUS_CAP + 4];          // 20 KB; reused as Ws (16 KB) in mm phase
    __shared__ float xT[XSTR * DIM];           // 17.4 KB
    float* Ws = (float*)lsw;

    int tid = threadIdx.x;
    int base = blockIdx.x * FUS_NPB;
    if (tid <= FUS_NPB) {
        int n = base + tid;
        soffs[tid] = offs[n < N ? n : N];
    }
    if (tid < FUS_NPB) {
        int n = base + tid;
        adl[tid] = (n < N) ? adp[n] : 0.f;
    }
    __syncthreads();
    int estart = soffs[0];
    int nE = soffs[FUS_NPB] - estart;
    bool inLds = (nE <= FUS_CAP);
    if (inLds) {
        for (int i = tid; i < nE; i += 512) {
            int2 sd = csr_sd[estart + i];
            float e = asp[sd.x] + adl[sd.y - base];
            e = (e > 0.f) ? e : 0.2f * e;
            lsw[i] = make_int2(sd.x, __builtin_bit_cast(int, expf(e)));
        }
        if (tid < 4) lsw[nE + tid] = make_int2(0, 0);
    }
    __syncthreads();

    int li = tid >> 3, fg = tid & 7;           // one 8-lane group per node
    int node = base + li;
    int ls = soffs[li] - estart;
    int deg = soffs[li + 1] - soffs[li];

    float a0 = 0.f, a1 = 0.f, a2 = 0.f, a3 = 0.f;
    float a4 = 0.f, a5 = 0.f, a6 = 0.f, a7 = 0.f, sw = 0.f;
    if (inLds) {
        for (int eb = 0; eb < deg; eb += 4) {
            int t = ls + eb;
            int2 eA = lsw[t], eB = lsw[t + 1], eC = lsw[t + 2], eD = lsw[t + 3];
            float wA = __builtin_bit_cast(float, eA.y);
            float wB = (eb + 1 < deg) ? __builtin_bit_cast(float, eB.y) : 0.f;
            float wC = (eb + 2 < deg) ? __builtin_bit_cast(float, eC.y) : 0.f;
            float wD = (eb + 3 < deg) ? __builtin_bit_cast(float, eD.y) : 0.f;
            const uint4 hA = *(const uint4*)(hbp + ((size_t)eA.x << 5) + (fg << 2));
            const uint4 hB = *(const uint4*)(hbp + ((size_t)eB.x << 5) + (fg << 2));
            const uint4 hC = *(const uint4*)(hbp + ((size_t)eC.x << 5) + (fg << 2));
            const uint4 hD = *(const uint4*)(hbp + ((size_t)eD.x << 5) + (fg << 2));
            sw += wA + wB + wC + wD;
            a0 += wA * bflo(hA.x) + wB * bflo(hB.x) + wC * bflo(hC.x) + wD * bflo(hD.x);
            a1 += wA * bfhi(hA.x) + wB * bfhi(hB.x) + wC * bfhi(hC.x) + wD * bfhi(hD.x);
            a2 += wA * bflo(hA.y) + wB * bflo(hB.y) + wC * bflo(hC.y) + wD * bflo(hD.y);
            a3 += wA * bfhi(hA.y) + wB * bfhi(hB.y) + wC * bfhi(hC.y) + wD * bfhi(hD.y);
            a4 += wA * bflo(hA.z) + wB * bflo(hB.z) + wC * bflo(hC.z) + wD * bflo(hD.z);
            a5 += wA * bfhi(hA.z) + wB * bfhi(hB.z) + wC * bfhi(hC.z) + wD * bfhi(hD.z);
            a6 += wA * bflo(hA.w) + wB * bflo(hB.w) + wC * bflo(hC.w) + wD * bflo(hD.w);
            a7 += wA * bfhi(hA.w) + wB * bfhi(hB.w) + wC * bfhi(hC.w) + wD * bfhi(hD.w);
        }
    } else {
        float adi = adl[li];
        for (int eb = 0; eb < deg; eb += 4) {
            int t = estart + ls + eb;
            float wv[4]; int sv[4];
            #pragma unroll
            for (int k = 0; k < 4; ++k) {
                int2 sd = (eb + k < deg) ? csr_sd[t + k] : make_int2(0, 0);
                int s = sd.x; s = s < 0 ? 0 : (s >= N ? N - 1 : s);
                float e = asp[s] + adi;
                e = (e > 0.f) ? e : 0.2f * e;
                wv[k] = (eb + k < deg) ? expf(e) : 0.f;
                sv[k] = s;
            }
            #pragma unroll
            for (int k = 0; k < 4; ++k) {
                const uint4 hv = *(const uint4*)(hbp + ((size_t)sv[k] << 5) + (fg << 2));
                sw += wv[k];
                a0 += wv[k] * bflo(hv.x); a1 += wv[k] * bfhi(hv.x);
                a2 += wv[k] * bflo(hv.y); a3 += wv[k] * bfhi(hv.y);
                a4 += wv[k] * bflo(hv.z); a5 += wv[k] * bfhi(hv.z);
                a6 += wv[k] * bflo(hv.w); a7 += wv[k] * bfhi(hv.w);
            }
        }
    }

    float inv = 1.f / (sw + 1e-16f);
    const float4 b0 = *(const float4*)(bias + (fg << 3));
    const float4 b1 = *(const float4*)(bias + (fg << 3) + 4);
    float o0 = a0 * inv + b0.x, o1 = a1 * inv + b0.y, o2 = a2 * inv + b0.z, o3 = a3 * inv + b0.w;
    float o4 = a4 * inv + b1.x, o5 = a5 * inv + b1.y, o6 = a6 * inv + b1.z, o7 = a7 * inv + b1.w;
    float n2 = o0 * o0 + o1 * o1 + o2 * o2 + o3 * o3 + o4 * o4 + o5 * o5 + o6 * o6 + o7 * o7;
    #pragma unroll
    for (int d = 1; d <= 4; d <<= 1) n2 += __shfl_xor(n2, d);   // across the 8 fg lanes
    float innrm = 1.f / fmaxf(sqrtf(n2), 1e-12f);
    if (node >= N) innrm = 0.f;                // keep xT clean for pad rows
    int kb = fg << 3;
    xT[(kb + 0) * XSTR + li] = fmaxf(o0 * innrm, 0.f);
    xT[(kb + 1) * XSTR + li] = fmaxf(o1 * innrm, 0.f);
    xT[(kb + 2) * XSTR + li] = fmaxf(o2 * innrm, 0.f);
    xT[(kb + 3) * XSTR + li] = fmaxf(o3 * innrm, 0.f);
    xT[(kb + 4) * XSTR + li] = fmaxf(o4 * innrm, 0.f);
    xT[(kb + 5) * XSTR + li] = fmaxf(o5 * innrm, 0.f);
    xT[(kb + 6) * XSTR + li] = fmaxf(o6 * innrm, 0.f);
    xT[(kb + 7) * XSTR + li] = fmaxf(o7 * innrm, 0.f);
    __syncthreads();                            // agg done; lsw region free

    const float4* W4 = (const float4*)W;
    float4* Ws4 = (float4*)Ws;
    Ws4[tid] = W4[tid];
    Ws4[tid + 512] = W4[tid + 512];
    __syncthreads();
    mm_core_512(xT, Ws, a_s, a_d, hbn, asn, adn, base, N);
}

// ---------------- per-wave MLP + log_softmax (graph finalize) ----------------
__device__ __forceinline__ void mlp_wave(int g, float gv, int lane,
                                         const float* __restrict__ fc1w, const float* __restrict__ fc1b,
                                         const float* __restrict__ fc2w, const float* __restrict__ fc2b,
                                         float* __restrict__ out) {
    float t = fc1b[lane];
    #pragma unroll 8
    for (int k = 0; k < DIM; ++k) t += __shfl(gv, k) * fc1w[k * DIM + lane];
    t = fmaxf(t, 0.f);
    float o = (lane < CNUM) ? fc2b[lane] : 0.f;
    #pragma unroll 8
    for (int k = 0; k < DIM; ++k) {
        float tk = __shfl(t, k);
        if (lane < CNUM) o += tk * fc2w[k * CNUM + lane];
    }
    float mx = -1e30f;
    #pragma unroll
    for (int c = 0; c < CNUM; ++c) mx = fmaxf(mx, __shfl(o, c));
    float ss = 0.f;
    #pragma unroll
    for (int c = 0; c < CNUM; ++c) ss += expf(__shfl(o, c) - mx);
    if (lane < CNUM) out[g * CNUM + lane] = o - mx - logf(ss);
}

// ---------------- fused final agg + global_add_pool + MLP ----------------
// Final-layer agg keeps node outputs in LDS (f32), sums per-graph segments,
// atomicAdds into gbuf[G][64], then per-graph arrival counters: the last
// block to contribute to graph g runs its MLP+log_softmax (wave 0). Sweeper
// block (bid==nblk) finalizes empty graphs. No oAb round-trip, no spins.
#define AGG_NPB 64
#define AGG_CAP 2560
__global__ __launch_bounds__(512) void agg_pool(const unsigned* __restrict__ hb,
                                                const int2* __restrict__ csr_sd,
                                                const float* __restrict__ as_,
                                                const float* __restrict__ ad_,
                                                const int* __restrict__ offs,
                                                const float* __restrict__ bias,
                                                const int* __restrict__ batch,
                                                const int* __restrict__ gstart,
                                                float* __restrict__ gbuf,
                                                int* __restrict__ gcnt,
                                                const float* __restrict__ fc1w, const float* __restrict__ fc1b,
                                                const float* __restrict__ fc2w, const float* __restrict__ fc2b,
                                                float* __restrict__ out, int N, int nblk) {
    if ((int)blockIdx.x == nblk) {
        // sweeper: finalize graphs with zero nodes (gvec = 0)
        if (threadIdx.x < 64) {
            int lane = threadIdx.x;
            for (int g = 0; g < GNUM; ++g)
                if (gstart[g + 1] == gstart[g])
                    mlp_wave(g, 0.f, lane, fc1w, fc1b, fc2w, fc2b, out);
        }
        return;
    }
    __shared__ int soffs[AGG_NPB + 1];
    __shared__ float adl[AGG_NPB];
    __shared__ int2 lsw[AGG_CAP + 4];
    __shared__ float nodeout[64 * 66];         // stride 66 to spread banks
    __shared__ int bgr[64];
    __shared__ int fing[64];
    __shared__ int nfin;
    int tid = threadIdx.x;
    int base = blockIdx.x * AGG_NPB;
    if (tid == 0) nfin = 0;
    if (tid <= AGG_NPB) {
        int n = base + tid;
        soffs[tid] = offs[n < N ? n : N];
    }
    if (tid < AGG_NPB) {
        int n = base + tid;
        adl[tid] = (n < N) ? ad_[n] : 0.f;
        bgr[tid] = (n < N) ? batch[n] : -1;
    }
    __syncthreads();
    int estart = soffs[0];
    int nE = soffs[AGG_NPB] - estart;
    bool inLds = (nE <= AGG_CAP);
    if (inLds) {
        for (int i = tid; i < nE; i += 512) {
            int2 sd = csr_sd[estart + i];
            float e = as_[sd.x] + adl[sd.y - base];
            e = (e > 0.f) ? e : 0.2f * e;
            lsw[i] = make_int2(sd.x, __builtin_bit_cast(int, expf(e)));
        }
        if (tid < 4) lsw[nE + tid] = make_int2(0, 0);
    }
    __syncthreads();

    int li = tid >> 3, fg = tid & 7;
    int node = base + li;
    int ls = soffs[li] - estart;
    int deg = soffs[li + 1] - soffs[li];

    float a0 = 0.f, a1 = 0.f, a2 = 0.f, a3 = 0.f;
    float a4 = 0.f, a5 = 0.f, a6 = 0.f, a7 = 0.f, sw = 0.f;
    if (inLds) {
        for (int eb = 0; eb < deg; eb += 4) {
            int t = ls + eb;
            int2 eA = lsw[t], eB = lsw[t + 1], eC = lsw[t + 2], eD = lsw[t + 3];
            float wA = __builtin_bit_cast(float, eA.y);
            float wB = (eb + 1 < deg) ? __builtin_bit_cast(float, eB.y) : 0.f;
            float wC = (eb + 2 < deg) ? __builtin_bit_cast(float, eC.y) : 0.f;
            float wD = (eb + 3 < deg) ? __builtin_bit_cast(float, eD.y) : 0.f;
            const uint4 hA = *(const uint4*)(hb + ((size_t)eA.x << 5) + (fg << 2));
            const uint4 hB = *(const uint4*)(hb + ((size_t)eB.x << 5) + (fg << 2));
            const uint4 hC = *(const uint4*)(hb + ((size_t)eC.x << 5) + (fg << 2));
            const uint4 hD = *(const uint4*)(hb + ((size_t)eD.x << 5) + (fg << 2));
            sw += wA + wB + wC + wD;
            a0 += wA * bflo(hA.x) + wB * bflo(hB.x) + wC * bflo(hC.x) + wD * bflo(hD.x);
            a1 += wA * bfhi(hA.x) + wB * bfhi(hB.x) + wC * bfhi(hC.x) + wD * bfhi(hD.x);
            a2 += wA * bflo(hA.y) + wB * bflo(hB.y) + wC * bflo(hC.y) + wD * bflo(hD.y);
            a3 += wA * bfhi(hA.y) + wB * bfhi(hB.y) + wC * bfhi(hC.y) + wD * bfhi(hD.y);
            a4 += wA * bflo(hA.z) + wB * bflo(hB.z) + wC * bflo(hC.z) + wD * bflo(hD.z);
            a5 += wA * bfhi(hA.z) + wB * bfhi(hB.z) + wC * bfhi(hC.z) + wD * bfhi(hD.z);
            a6 += wA * bflo(hA.w) + wB * bflo(hB.w) + wC * bflo(hC.w) + wD * bflo(hD.w);
            a7 += wA * bfhi(hA.w) + wB * bfhi(hB.w) + wC * bfhi(hC.w) + wD * bfhi(hD.w);
        }
    } else {
        float adi = adl[li];
        for (int eb = 0; eb < deg; eb += 4) {
            int t = estart + ls + eb;
            float wv[4]; int sv[4];
            #pragma unroll
            for (int k = 0; k < 4; ++k) {
                int2 sd = (eb + k < deg) ? csr_sd[t + k] : make_int2(0, 0);
                int s = sd.x; s = s < 0 ? 0 : (s >= N ? N - 1 : s);
                float e = as_[s] + adi;
                e = (e > 0.f) ? e : 0.2f * e;
                wv[k] = (eb + k < deg) ? expf(e) : 0.f;
                sv[k] = s;
            }
            #pragma unroll
            for (int k = 0; k < 4; ++k) {
                const uint4 hv = *(const uint4*)(hb + ((size_t)sv[k] << 5) + (fg << 2));
                sw += wv[k];
                a0 += wv[k] * bflo(hv.x); a1 += wv[k] * bfhi(hv.x);
                a2 += wv[k] * bflo(hv.y); a3 += wv[k] * bfhi(hv.y);
                a4 += wv[k] * bflo(hv.z); a5 += wv[k] * bfhi(hv.z);
                a6 += wv[k] * bflo(hv.w); a7 += wv[k] * bfhi(hv.w);
            }
        }
    }

    float inv = 1.f / (sw + 1e-16f);
    const float4 b0 = *(const float4*)(bias + (fg << 3));
    const float4 b1 = *(const float4*)(bias + (fg << 3) + 4);
    float o0 = a0 * inv + b0.x, o1 = a1 * inv + b0.y, o2 = a2 * inv + b0.z, o3 = a3 * inv + b0.w;
    float o4 = a4 * inv + b1.x, o5 = a5 * inv + b1.y, o6 = a6 * inv + b1.z, o7 = a7 * inv + b1.w;
    float n2 = o0 * o0 + o1 * o1 + o2 * o2 + o3 * o3 + o4 * o4 + o5 * o5 + o6 * o6 + o7 * o7;
    #pragma unroll
    for (int d = 1; d <= 4; d <<= 1) n2 += __shfl_xor(n2, d);
    float innrm = 1.f / fmaxf(sqrtf(n2), 1e-12f);
    if (node >= N) innrm = 0.f;
    int co = fg << 3;
    nodeout[li * 66 + co + 0] = fmaxf(o0 * innrm, 0.f);
    nodeout[li * 66 + co + 1] = fmaxf(o1 * innrm, 0.f);
    nodeout[li * 66 + co + 2] = fmaxf(o2 * innrm, 0.f);
    nodeout[li * 66 + co + 3] = fmaxf(o3 * innrm, 0.f);
    nodeout[li * 66 + co + 4] = fmaxf(o4 * innrm, 0.f);
    nodeout[li * 66 + co + 5] = fmaxf(o5 * innrm, 0.f);
    nodeout[li * 66 + co + 6] = fmaxf(o6 * innrm, 0.f);
    nodeout[li * 66 + co + 7] = fmaxf(o7 * innrm, 0.f);
    __syncthreads();

    // wave 0: per-graph segment sums -> gbuf atomics -> arrival counters
    if (tid < 64) {
        int lane = tid;
        int nvalid = N - base; if (nvalid > 64) nvalid = 64;
        int r = 0;
        while (r < nvalid) {
            int g = bgr[r];
            int re = r;
            while (re < nvalid && bgr[re] == g) ++re;
            float s = 0.f;
            for (int q = r; q < re; ++q) s += nodeout[q * 66 + lane];
            atomicAdd(&gbuf[g * 64 + lane], s);
            __threadfence();                    // wave's gbuf adds before counter
            if (lane == 0) {
                int fb = gstart[g] >> 6;
                int lb = (gstart[g + 1] - 1) >> 6;
                int expected = lb - fb + 1;
                int old = atomicAdd(&gcnt[g], 1);
                if (old == expected - 1) { fing[nfin] = g; ++nfin; }
            }
            r = re;
        }
    }
    __syncthreads();

    // wave 0: finalize graphs this block closed
    if (tid < 64) {
        int lane = tid;
        int nf = nfin;
        for (int fi = 0; fi < nf; ++fi) {
            int g = fing[fi];
            __threadfence();
            float gv = __hip_atomic_load(&gbuf[g * 64 + lane], __ATOMIC_ACQUIRE, __HIP_MEMORY_SCOPE_AGENT);
            mlp_wave(g, gv, lane, fc1w, fc1b, fc2w, fc2b, out);
        }
    }
}

// ---------------- launch ----------------
static inline size_t align256(size_t x) { return (x + 255) & ~size_t(255); }

extern "C" void kernel_launch(void* const* d_in, const int* in_sizes, int n_in,
                              void* d_out, int out_size, void* d_ws, size_t ws_size,
                              hipStream_t stream) {
    const float* x     = (const float*)d_in[0];
    const int*   ei    = (const int*)d_in[1];
    const int*   batch = (const int*)d_in[2];
    const float* w1  = (const float*)d_in[3];
    const float* as1 = (const float*)d_in[4];
    const float* ad1 = (const float*)d_in[5];
    const float* b1  = (const float*)d_in[6];
    const float* w2  = (const float*)d_in[7];
    const float* as2 = (const float*)d_in[8];
    const float* ad2 = (const float*)d_in[9];
    const float* b2  = (const float*)d_in[10];
    const float* w3  = (const float*)d_in[11];
    const float* as3 = (const float*)d_in[12];
    const float* ad3 = (const float*)d_in[13];
    const float* b3  = (const float*)d_in[14];
    const float* fc1w = (const float*)d_in[15];
    const float* fc1b = (const float*)d_in[16];
    const float* fc2w = (const float*)d_in[17];
    const float* fc2b = (const float*)d_in[18];
    float* out = (float*)d_out;

    int N  = in_sizes[0] / DIM;
    int E  = in_sizes[1] / 2;
    int EP = E + N;
    int nb = (N + 255) / 256;   // scan blocks (<= 256 for N <= 65536)

    // workspace carve (zero-init region contiguous: deg, gcnt, gbuf)
    char* p = (char*)d_ws;
    unsigned* hbA = (unsigned*)p; p += align256(sizeof(unsigned) * (size_t)N * (DIM / 2));
    unsigned* hbB = (unsigned*)p; p += align256(sizeof(unsigned) * (size_t)N * (DIM / 2));
    float* asA  = (float*)p; p += align256(sizeof(float) * (size_t)N);
    float* adA  = (float*)p; p += align256(sizeof(float) * (size_t)N);
    float* asB  = (float*)p; p += align256(sizeof(float) * (size_t)N);
    float* adB  = (float*)p; p += align256(sizeof(float) * (size_t)N);
    char* zstart = p;
    int*      deg  = (int*)p;      p += align256(sizeof(int) * (size_t)N);
    int*      gcnt = (int*)p;      p += align256(sizeof(int) * (size_t)GNUM);
    float*    gbuf = (float*)p;    p += align256(sizeof(float) * (size_t)GNUM * DIM);
    char* zend = p;
    int*   offs = (int*)p;   p += align256(sizeof(int) * (size_t)(N + 1));
    int*   rank = (int*)p;   p += align256(sizeof(int) * (size_t)EP);
    int2*  csr_sd = (int2*)p; p += align256(sizeof(int2) * (size_t)EP);
    int*   part = (int*)p;   p += align256(sizeof(int) * (size_t)nb);
    int*   gst  = (int*)p;   p += align256(sizeof(int) * (size_t)(GNUM + 1));

    int nfb  = (N + FUS_NPB - 1) / FUS_NPB;   // fused agg+mm blocks
    int nblk = (N + AGG_NPB - 1) / AGG_NPB;   // final agg_pool blocks
    int nbt = (N + 63) / 64;                  // mm tiles
    int epBlocks = (EP + 511) / 512;          // scatter blocks

    // zero-init: deg + graph counters/sums, one fill
    hipMemsetAsync(zstart, 0, (size_t)(zend - zstart), stream);
    deg_rank_kernel<<<(EP + 255) / 256, 256, 0, stream>>>(ei, E, N, deg, rank);
    scan_misc<<<nb + 1, 256, 0, stream>>>(deg, part, N, nb, batch, N, gst);
    scan_down<<<nb, 256, 0, stream>>>(deg, part, offs, N);

    // layer 1 mm (+ CSR scatter overlapped)
    mm_fill<<<nbt + epBlocks, 512, 0, stream>>>(x, w1, as1, ad1, hbA, asA, adA, N, nbt,
                                                ei, rank, E, offs, csr_sd);
    // fused agg(1)+mm(2), agg(2)+mm(3)
    agg_mm<<<nfb, 512, 0, stream>>>(hbA, csr_sd, asA, adA, offs, b1, w2, as2, ad2,
                                    hbB, asB, adB, N);
    agg_mm<<<nfb, 512, 0, stream>>>(hbB, csr_sd, asB, adB, offs, b2, w3, as3, ad3,
                                    hbA, asA, adA, N);
    // fused final agg + pool + MLP head
    agg_pool<<<nblk + 1, 512, 0, stream>>>(hbA, csr_sd, asA, adA, offs, b3, batch, gst,
                                           gbuf, gcnt, fc1w, fc1b, fc2w, fc2b, out, N, nblk);
}

// Round 7
// 261.006 us; speedup vs baseline: 1.0297x; 1.0297x over previous
//
#include <hip/hip_runtime.h>
#include <hip/hip_bf16.h>
#include <math.h>

#define DIM 64
#define GNUM 256
#define CNUM 10

// bf16x2 pack/unpack (RNE). h intermediates are bf16 for gather traffic;
// alpha/softmax math stays f32.
__device__ __forceinline__ unsigned bfpack(float a, float b) {
    unsigned ua = __builtin_bit_cast(unsigned, a);
    unsigned ub = __builtin_bit_cast(unsigned, b);
    ua += 0x7fffu + ((ua >> 16) & 1u);
    ub += 0x7fffu + ((ub >> 16) & 1u);
    return (ua >> 16) | (ub & 0xffff0000u);
}
__device__ __forceinline__ float bflo(unsigned u) { return __builtin_bit_cast(float, u << 16); }
__device__ __forceinline__ float bfhi(unsigned u) { return __builtin_bit_cast(float, u & 0xffff0000u); }
__device__ __forceinline__ float bfs(unsigned short u) { return __builtin_bit_cast(float, (unsigned)u << 16); }

// ---------------- CSR build ----------------
__global__ void deg_rank_kernel(const int* __restrict__ ei, int E, int N,
                                int* __restrict__ deg, int* __restrict__ rank) {
    int i = blockIdx.x * blockDim.x + threadIdx.x;
    int EP = E + N;
    if (i >= EP) return;
    int d = (i < E) ? ei[E + i] : (i - E);   // row 1 of edge_index = dst; self loops appended
    rank[i] = atomicAdd(&deg[d], 1);
}

// scan_blocks + graph_bounds, role-split by blockIdx.
__global__ __launch_bounds__(256) void scan_misc(const int* __restrict__ deg, int* __restrict__ part, int n, int nb,
                                                 const int* __restrict__ batch, int N,
                                                 int* __restrict__ gstart) {
    int bid = blockIdx.x;
    if (bid < nb) {
        __shared__ int ws[4];
        int i = bid * 256 + threadIdx.x;
        int v = (i < n) ? deg[i] : 0;
        #pragma unroll
        for (int d = 32; d >= 1; d >>= 1) v += __shfl_xor(v, d);
        if ((threadIdx.x & 63) == 0) ws[threadIdx.x >> 6] = v;
        __syncthreads();
        if (threadIdx.x == 0) part[bid] = ws[0] + ws[1] + ws[2] + ws[3];
    } else {
        for (int g = threadIdx.x; g <= GNUM; g += 256) {
            int lo = 0, hi = N;
            while (lo < hi) { int mid = (lo + hi) >> 1; if (batch[mid] < g) lo = mid + 1; else hi = mid; }
            gstart[g] = lo;
        }
    }
}

// scan_down with the top-level scan fused (nb <= 256 for N <= 65536).
__global__ __launch_bounds__(256) void scan_down(const int* __restrict__ deg, const int* __restrict__ part,
                                                 int* __restrict__ offs, int n) {
    __shared__ int ws[4];
    __shared__ int base_s;
    int tid = threadIdx.x, lane = tid & 63, wid = tid >> 6;
    int pv = (tid < (int)blockIdx.x) ? part[tid] : 0;
    #pragma unroll
    for (int d = 32; d >= 1; d >>= 1) pv += __shfl_xor(pv, d);
    if (lane == 0) ws[wid] = pv;
    __syncthreads();
    if (tid == 0) base_s = ws[0] + ws[1] + ws[2] + ws[3];
    __syncthreads();
    int i = blockIdx.x * 256 + tid;
    int v = (i < n) ? deg[i] : 0;
    int x = v;
    #pragma unroll
    for (int d = 1; d < 64; d <<= 1) { int t = __shfl_up(x, d); if (lane >= d) x += t; }
    if (lane == 63) ws[wid] = x;
    __syncthreads();
    int add = base_s;
    for (int w = 0; w < wid; ++w) add += ws[w];
    if (i < n) offs[i] = add + x - v;
    if (i == n - 1) offs[n] = add + x;
}

// ---------------- pipelined 8-wide gather (R15) ----------------
// 8 edges per round: 8 LDS pack-reads (broadcast within the 8-lane group)
// then 8 independent uint4 gathers in flight before the FMA block. Halves
// the number of serialized latency rounds vs 4-wide (avg deg 17 -> 2.5
// rounds) and doubles outstanding loads per wave. Over-reads within the
// block's LDS slice are masked by w=0 (pad of 8 zero entries past nE).
__device__ __forceinline__ void gat_gather8(const unsigned* __restrict__ hb,
                                            const int2* __restrict__ lsw,
                                            int ls, int deg, int fg,
                                            float& a0, float& a1, float& a2, float& a3,
                                            float& a4, float& a5, float& a6, float& a7,
                                            float& sw) {
    for (int eb = 0; eb < deg; eb += 8) {
        int t = ls + eb;
        int2 e0 = lsw[t],     e1 = lsw[t + 1], e2 = lsw[t + 2], e3 = lsw[t + 3];
        int2 e4 = lsw[t + 4], e5 = lsw[t + 5], e6 = lsw[t + 6], e7 = lsw[t + 7];
        int rem = deg - eb;
        float w0 = __builtin_bit_cast(float, e0.y);
        float w1 = (rem > 1) ? __builtin_bit_cast(float, e1.y) : 0.f;
        float w2 = (rem > 2) ? __builtin_bit_cast(float, e2.y) : 0.f;
        float w3 = (rem > 3) ? __builtin_bit_cast(float, e3.y) : 0.f;
        float w4 = (rem > 4) ? __builtin_bit_cast(float, e4.y) : 0.f;
        float w5 = (rem > 5) ? __builtin_bit_cast(float, e5.y) : 0.f;
        float w6 = (rem > 6) ? __builtin_bit_cast(float, e6.y) : 0.f;
        float w7 = (rem > 7) ? __builtin_bit_cast(float, e7.y) : 0.f;
        const uint4 h0 = *(const uint4*)(hb + ((size_t)e0.x << 5) + (fg << 2));
        const uint4 h1 = *(const uint4*)(hb + ((size_t)e1.x << 5) + (fg << 2));
        const uint4 h2 = *(const uint4*)(hb + ((size_t)e2.x << 5) + (fg << 2));
        const uint4 h3 = *(const uint4*)(hb + ((size_t)e3.x << 5) + (fg << 2));
        const uint4 h4 = *(const uint4*)(hb + ((size_t)e4.x << 5) + (fg << 2));
        const uint4 h5 = *(const uint4*)(hb + ((size_t)e5.x << 5) + (fg << 2));
        const uint4 h6 = *(const uint4*)(hb + ((size_t)e6.x << 5) + (fg << 2));
        const uint4 h7 = *(const uint4*)(hb + ((size_t)e7.x << 5) + (fg << 2));
        sw += ((w0 + w1) + (w2 + w3)) + ((w4 + w5) + (w6 + w7));
        a0 += w0 * bflo(h0.x) + w1 * bflo(h1.x) + w2 * bflo(h2.x) + w3 * bflo(h3.x)
            + w4 * bflo(h4.x) + w5 * bflo(h5.x) + w6 * bflo(h6.x) + w7 * bflo(h7.x);
        a1 += w0 * bfhi(h0.x) + w1 * bfhi(h1.x) + w2 * bfhi(h2.x) + w3 * bfhi(h3.x)
            + w4 * bfhi(h4.x) + w5 * bfhi(h5.x) + w6 * bfhi(h6.x) + w7 * bfhi(h7.x);
        a2 += w0 * bflo(h0.y) + w1 * bflo(h1.y) + w2 * bflo(h2.y) + w3 * bflo(h3.y)
            + w4 * bflo(h4.y) + w5 * bflo(h5.y) + w6 * bflo(h6.y) + w7 * bflo(h7.y);
        a3 += w0 * bfhi(h0.y) + w1 * bfhi(h1.y) + w2 * bfhi(h2.y) + w3 * bfhi(h3.y)
            + w4 * bfhi(h4.y) + w5 * bfhi(h5.y) + w6 * bfhi(h6.y) + w7 * bfhi(h7.y);
        a4 += w0 * bflo(h0.z) + w1 * bflo(h1.z) + w2 * bflo(h2.z) + w3 * bflo(h3.z)
            + w4 * bflo(h4.z) + w5 * bflo(h5.z) + w6 * bflo(h6.z) + w7 * bflo(h7.z);
        a5 += w0 * bfhi(h0.z) + w1 * bfhi(h1.z) + w2 * bfhi(h2.z) + w3 * bfhi(h3.z)
            + w4 * bfhi(h4.z) + w5 * bfhi(h5.z) + w6 * bfhi(h6.z) + w7 * bfhi(h7.z);
        a6 += w0 * bflo(h0.w) + w1 * bflo(h1.w) + w2 * bflo(h2.w) + w3 * bflo(h3.w)
            + w4 * bflo(h4.w) + w5 * bflo(h5.w) + w6 * bflo(h6.w) + w7 * bflo(h7.w);
        a7 += w0 * bfhi(h0.w) + w1 * bfhi(h1.w) + w2 * bfhi(h2.w) + w3 * bfhi(h3.w)
            + w4 * bfhi(h4.w) + w5 * bfhi(h5.w) + w6 * bfhi(h6.w) + w7 * bfhi(h7.w);
    }
}

// ---------------- 512-thread 64x64 mm pieces ----------------
#define XSTR 68
__device__ __forceinline__ void mm_core_512(const float* __restrict__ xT, const float* __restrict__ Ws,
                                            const float* __restrict__ a_s, const float* __restrict__ a_d,
                                            unsigned* __restrict__ hbn, float* __restrict__ asn,
                                            float* __restrict__ adn, int base, int N) {
    int tid = threadIdx.x;
    int tx = tid & 15, ty = tid >> 4;          // ty 0..31
    int c0 = tx << 2, r0 = ty << 1;
    float acc[2][4] = {{0.f}};
    #pragma unroll 8
    for (int k = 0; k < DIM; ++k) {
        float2 xv = *(const float2*)(xT + k * XSTR + r0);
        float4 wv = *(const float4*)(Ws + k * DIM + c0);
        acc[0][0] += xv.x * wv.x; acc[0][1] += xv.x * wv.y; acc[0][2] += xv.x * wv.z; acc[0][3] += xv.x * wv.w;
        acc[1][0] += xv.y * wv.x; acc[1][1] += xv.y * wv.y; acc[1][2] += xv.y * wv.z; acc[1][3] += xv.y * wv.w;
    }
    float4 av = *(const float4*)(a_s + c0);
    float4 dv = *(const float4*)(a_d + c0);
    #pragma unroll
    for (int ri = 0; ri < 2; ++ri) {
        int grow = base + r0 + ri;
        float s1 = acc[ri][0] * av.x + acc[ri][1] * av.y + acc[ri][2] * av.z + acc[ri][3] * av.w;
        float s2 = acc[ri][0] * dv.x + acc[ri][1] * dv.y + acc[ri][2] * dv.z + acc[ri][3] * dv.w;
        #pragma unroll
        for (int d = 1; d <= 8; d <<= 1) { s1 += __shfl_xor(s1, d); s2 += __shfl_xor(s2, d); }
        if (grow < N) {
            uint2 o;
            o.x = bfpack(acc[ri][0], acc[ri][1]);
            o.y = bfpack(acc[ri][2], acc[ri][3]);
            *(uint2*)(hbn + ((size_t)grow << 5) + (tx << 1)) = o;
            if (tx == 0) { asn[grow] = s1; adn[grow] = s2; }
        }
    }
}

// layer-1 mm (f32 input, 512 threads) + atomic-free CSR scatter, role-split.
__global__ __launch_bounds__(512) void mm_fill(const float* __restrict__ in, const float* __restrict__ W,
                                               const float* __restrict__ a_s, const float* __restrict__ a_d,
                                               unsigned* __restrict__ hb, float* __restrict__ as_,
                                               float* __restrict__ ad_, int N, int nbt,
                                               const int* __restrict__ ei, const int* __restrict__ rank, int E,
                                               const int* __restrict__ offs, int2* __restrict__ csr_sd) {
    int bid = blockIdx.x;
    if (bid < nbt) {
        __shared__ float Ws[DIM * DIM];
        __shared__ float xT[XSTR * DIM];
        int tid = threadIdx.x;
        int base = bid * 64;

        const float4* W4 = (const float4*)W;
        float4* Ws4 = (float4*)Ws;
        Ws4[tid] = W4[tid];
        Ws4[tid + 512] = W4[tid + 512];

        {
            int row = tid >> 3;
            int kb = (tid & 7) << 3;
            int grow = base + row;
            int crow = grow < N ? grow : N - 1;
            const float4* xr = (const float4*)(in + ((size_t)crow << 6) + kb);
            float4 v0 = xr[0], v1 = xr[1];
            xT[(kb + 0) * XSTR + row] = v0.x;  xT[(kb + 1) * XSTR + row] = v0.y;
            xT[(kb + 2) * XSTR + row] = v0.z;  xT[(kb + 3) * XSTR + row] = v0.w;
            xT[(kb + 4) * XSTR + row] = v1.x;  xT[(kb + 5) * XSTR + row] = v1.y;
            xT[(kb + 6) * XSTR + row] = v1.z;  xT[(kb + 7) * XSTR + row] = v1.w;
        }
        __syncthreads();
        mm_core_512(xT, Ws, a_s, a_d, hb, as_, ad_, base, N);
    } else {
        int i = (bid - nbt) * 512 + threadIdx.x;
        int EP = E + N;
        if (i >= EP) return;
        int s, d;
        if (i < E) { s = ei[i]; d = ei[E + i]; } else { s = i - E; d = i - E; }
        csr_sd[offs[d] + rank[i]] = make_int2(s, d);
    }
}

// ---------------- fused agg(layer k) + mm(layer k+1), 512 threads ----------------
#define FUS_NPB 64
#define FUS_CAP 2560
__global__ __launch_bounds__(512) void agg_mm(const unsigned* __restrict__ hbp,
                                              const int2* __restrict__ csr_sd,
                                              const float* __restrict__ asp,
                                              const float* __restrict__ adp,
                                              const int* __restrict__ offs,
                                              const float* __restrict__ bias,
                                              const float* __restrict__ W,
                                              const float* __restrict__ a_s,
                                              const float* __restrict__ a_d,
                                              unsigned* __restrict__ hbn,
                                              float* __restrict__ asn,
                                              float* __restrict__ adn, int N) {
    __shared__ int soffs[FUS_NPB + 1];
    __shared__ float adl[FUS_NPB];
    __shared__ int2 lsw[FUS_CAP + 8];          // 20 KB; reused as Ws (16 KB) in mm phase
    __shared__ float xT[XSTR * DIM];           // 17.4 KB
    float* Ws = (float*)lsw;

    int tid = threadIdx.x;
    int base = blockIdx.x * FUS_NPB;
    if (tid <= FUS_NPB) {
        int n = base + tid;
        soffs[tid] = offs[n < N ? n : N];
    }
    if (tid < FUS_NPB) {
        int n = base + tid;
        adl[tid] = (n < N) ? adp[n] : 0.f;
    }
    __syncthreads();
    int estart = soffs[0];
    int nE = soffs[FUS_NPB] - estart;
    bool inLds = (nE <= FUS_CAP);
    if (inLds) {
        for (int i = tid; i < nE; i += 512) {
            int2 sd = csr_sd[estart + i];
            float e = asp[sd.x] + adl[sd.y - base];
            e = (e > 0.f) ? e : 0.2f * e;
            lsw[i] = make_int2(sd.x, __builtin_bit_cast(int, expf(e)));
        }
        if (tid < 8) lsw[nE + tid] = make_int2(0, 0);
    }
    __syncthreads();

    int li = tid >> 3, fg = tid & 7;           // one 8-lane group per node
    int node = base + li;
    int ls = soffs[li] - estart;
    int deg = soffs[li + 1] - soffs[li];

    float a0 = 0.f, a1 = 0.f, a2 = 0.f, a3 = 0.f;
    float a4 = 0.f, a5 = 0.f, a6 = 0.f, a7 = 0.f, sw = 0.f;
    if (inLds) {
        gat_gather8(hbp, lsw, ls, deg, fg, a0, a1, a2, a3, a4, a5, a6, a7, sw);
    } else {
        float adi = adl[li];
        for (int eb = 0; eb < deg; eb += 4) {
            int t = estart + ls + eb;
            float wv[4]; int sv[4];
            #pragma unroll
            for (int k = 0; k < 4; ++k) {
                int2 sd = (eb + k < deg) ? csr_sd[t + k] : make_int2(0, 0);
                int s = sd.x; s = s < 0 ? 0 : (s >= N ? N - 1 : s);
                float e = asp[s] + adi;
                e = (e > 0.f) ? e : 0.2f * e;
                wv[k] = (eb + k < deg) ? expf(e) : 0.f;
                sv[k] = s;
            }
            #pragma unroll
            for (int k = 0; k < 4; ++k) {
                const uint4 hv = *(const uint4*)(hbp + ((size_t)sv[k] << 5) + (fg << 2));
                sw += wv[k];
                a0 += wv[k] * bflo(hv.x); a1 += wv[k] * bfhi(hv.x);
                a2 += wv[k] * bflo(hv.y); a3 += wv[k] * bfhi(hv.y);
                a4 += wv[k] * bflo(hv.z); a5 += wv[k] * bfhi(hv.z);
                a6 += wv[k] * bflo(hv.w); a7 += wv[k] * bfhi(hv.w);
            }
        }
    }

    float inv = 1.f / (sw + 1e-16f);
    const float4 b0 = *(const float4*)(bias + (fg << 3));
    const float4 b1 = *(const float4*)(bias + (fg << 3) + 4);
    float o0 = a0 * inv + b0.x, o1 = a1 * inv + b0.y, o2 = a2 * inv + b0.z, o3 = a3 * inv + b0.w;
    float o4 = a4 * inv + b1.x, o5 = a5 * inv + b1.y, o6 = a6 * inv + b1.z, o7 = a7 * inv + b1.w;
    float n2 = o0 * o0 + o1 * o1 + o2 * o2 + o3 * o3 + o4 * o4 + o5 * o5 + o6 * o6 + o7 * o7;
    #pragma unroll
    for (int d = 1; d <= 4; d <<= 1) n2 += __shfl_xor(n2, d);   // across the 8 fg lanes
    float innrm = 1.f / fmaxf(sqrtf(n2), 1e-12f);
    if (node >= N) innrm = 0.f;                // keep xT clean for pad rows
    int kb = fg << 3;
    xT[(kb + 0) * XSTR + li] = fmaxf(o0 * innrm, 0.f);
    xT[(kb + 1) * XSTR + li] = fmaxf(o1 * innrm, 0.f);
    xT[(kb + 2) * XSTR + li] = fmaxf(o2 * innrm, 0.f);
    xT[(kb + 3) * XSTR + li] = fmaxf(o3 * innrm, 0.f);
    xT[(kb + 4) * XSTR + li] = fmaxf(o4 * innrm, 0.f);
    xT[(kb + 5) * XSTR + li] = fmaxf(o5 * innrm, 0.f);
    xT[(kb + 6) * XSTR + li] = fmaxf(o6 * innrm, 0.f);
    xT[(kb + 7) * XSTR + li] = fmaxf(o7 * innrm, 0.f);
    __syncthreads();                            // agg done; lsw region free

    const float4* W4 = (const float4*)W;
    float4* Ws4 = (float4*)Ws;
    Ws4[tid] = W4[tid];
    Ws4[tid + 512] = W4[tid + 512];
    __syncthreads();
    mm_core_512(xT, Ws, a_s, a_d, hbn, asn, adn, base, N);
}

// ---------------- per-node softmax-aggregate (final layer, 512 threads) ----------------
#define AGG_NPB 64
#define AGG_CAP 2560
__global__ __launch_bounds__(512) void gat_agg(const unsigned* __restrict__ hb,
                                               const int2* __restrict__ csr_sd,
                                               const float* __restrict__ as_,
                                               const float* __restrict__ ad_,
                                               const int* __restrict__ offs,
                                               const float* __restrict__ bias,
                                               unsigned* __restrict__ outb, int N) {
    __shared__ int soffs[AGG_NPB + 1];
    __shared__ float adl[AGG_NPB];
    __shared__ int2 lsw[AGG_CAP + 8];
    int tid = threadIdx.x;
    int base = blockIdx.x * AGG_NPB;
    if (tid <= AGG_NPB) {
        int n = base + tid;
        soffs[tid] = offs[n < N ? n : N];
    }
    if (tid < AGG_NPB) {
        int n = base + tid;
        adl[tid] = (n < N) ? ad_[n] : 0.f;
    }
    __syncthreads();
    int estart = soffs[0];
    int nE = soffs[AGG_NPB] - estart;
    bool inLds = (nE <= AGG_CAP);
    if (inLds) {
        for (int i = tid; i < nE; i += 512) {
            int2 sd = csr_sd[estart + i];
            float e = as_[sd.x] + adl[sd.y - base];
            e = (e > 0.f) ? e : 0.2f * e;
            lsw[i] = make_int2(sd.x, __builtin_bit_cast(int, expf(e)));
        }
        if (tid < 8) lsw[nE + tid] = make_int2(0, 0);
    }
    __syncthreads();

    int li = tid >> 3, fg = tid & 7;
    int node = base + li;
    int ls = soffs[li] - estart;
    int deg = soffs[li + 1] - soffs[li];

    float a0 = 0.f, a1 = 0.f, a2 = 0.f, a3 = 0.f;
    float a4 = 0.f, a5 = 0.f, a6 = 0.f, a7 = 0.f, sw = 0.f;
    if (inLds) {
        gat_gather8(hb, lsw, ls, deg, fg, a0, a1, a2, a3, a4, a5, a6, a7, sw);
    } else {
        float adi = (node < N) ? ad_[node] : 0.f;
        for (int eb = 0; eb < deg; eb += 4) {
            int t = estart + ls + eb;
            float wv[4]; int sv[4];
            #pragma unroll
            for (int k = 0; k < 4; ++k) {
                int2 sd = (eb + k < deg) ? csr_sd[t + k] : make_int2(0, 0);
                int s = sd.x; s = s < 0 ? 0 : (s >= N ? N - 1 : s);
                float e = as_[s] + adi;
                e = (e > 0.f) ? e : 0.2f * e;
                wv[k] = (eb + k < deg) ? expf(e) : 0.f;
                sv[k] = s;
            }
            #pragma unroll
            for (int k = 0; k < 4; ++k) {
                const uint4 hv = *(const uint4*)(hb + ((size_t)sv[k] << 5) + (fg << 2));
                sw += wv[k];
                a0 += wv[k] * bflo(hv.x); a1 += wv[k] * bfhi(hv.x);
                a2 += wv[k] * bflo(hv.y); a3 += wv[k] * bfhi(hv.y);
                a4 += wv[k] * bflo(hv.z); a5 += wv[k] * bfhi(hv.z);
                a6 += wv[k] * bflo(hv.w); a7 += wv[k] * bfhi(hv.w);
            }
        }
    }

    float inv = 1.f / (sw + 1e-16f);
    const float4 b0 = *(const float4*)(bias + (fg << 3));
    const float4 b1 = *(const float4*)(bias + (fg << 3) + 4);
    float o0 = a0 * inv + b0.x, o1 = a1 * inv + b0.y, o2 = a2 * inv + b0.z, o3 = a3 * inv + b0.w;
    float o4 = a4 * inv + b1.x, o5 = a5 * inv + b1.y, o6 = a6 * inv + b1.z, o7 = a7 * inv + b1.w;
    float n2 = o0 * o0 + o1 * o1 + o2 * o2 + o3 * o3 + o4 * o4 + o5 * o5 + o6 * o6 + o7 * o7;
    #pragma unroll
    for (int d = 1; d <= 4; d <<= 1) n2 += __shfl_xor(n2, d);   // across the 8 fg lanes
    float innrm = 1.f / fmaxf(sqrtf(n2), 1e-12f);
    if (node < N) {
        uint4 o;
        o.x = bfpack(fmaxf(o0 * innrm, 0.f), fmaxf(o1 * innrm, 0.f));
        o.y = bfpack(fmaxf(o2 * innrm, 0.f), fmaxf(o3 * innrm, 0.f));
        o.z = bfpack(fmaxf(o4 * innrm, 0.f), fmaxf(o5 * innrm, 0.f));
        o.w = bfpack(fmaxf(o6 * innrm, 0.f), fmaxf(o7 * innrm, 0.f));
        *(uint4*)(outb + ((size_t)node << 5) + (fg << 2)) = o;
    }
}

// ---------------- fused global_add_pool + MLP + log_softmax ----------------
__global__ __launch_bounds__(256) void pool_mlp(const unsigned short* __restrict__ hb, const int* __restrict__ gstart,
                                                const float* __restrict__ fc1w, const float* __restrict__ fc1b,
                                                const float* __restrict__ fc2w, const float* __restrict__ fc2b,
                                                float* __restrict__ out) {
    __shared__ float W1[DIM * DIM];
    __shared__ float red[4 * DIM];
    __shared__ float tbuf[DIM];
    __shared__ float obuf[CNUM];
    int tid = threadIdx.x, lane = tid & 63, wv = tid >> 6;
    int gid = blockIdx.x;

    const float4* W4 = (const float4*)fc1w;
    float4* W1s = (float4*)W1;
    #pragma unroll
    for (int i = 0; i < 4; ++i) W1s[tid + 256 * i] = W4[tid + 256 * i];

    int s = gstart[gid], e = gstart[gid + 1];
    float acc = 0.f;
    for (int i = s + wv; i < e; i += 4) acc += bfs(hb[((size_t)i << 6) + lane]);
    red[wv * DIM + lane] = acc;
    __syncthreads();

    if (wv == 0) {
        float g = red[lane] + red[DIM + lane] + red[2 * DIM + lane] + red[3 * DIM + lane];
        float t = fc1b[lane];
        #pragma unroll
        for (int k = 0; k < DIM; ++k) t += __shfl(g, k) * W1[k * DIM + lane];
        t = fmaxf(t, 0.f);
        tbuf[lane] = t;
        float o = 0.f;
        if (lane < CNUM) {
            o = fc2b[lane];
            #pragma unroll
            for (int k = 0; k < DIM; ++k) o += tbuf[k] * fc2w[k * CNUM + lane];
            obuf[lane] = o;
        }
        if (lane < CNUM) {
            float mx = obuf[0];
            #pragma unroll
            for (int k = 1; k < CNUM; ++k) mx = fmaxf(mx, obuf[k]);
            float ssum = 0.f;
            #pragma unroll
            for (int k = 0; k < CNUM; ++k) ssum += expf(obuf[k] - mx);
            out[gid * CNUM + lane] = o - mx - logf(ssum);
        }
    }
}

// ---------------- launch ----------------
static inline size_t align256(size_t x) { return (x + 255) & ~size_t(255); }

extern "C" void kernel_launch(void* const* d_in, const int* in_sizes, int n_in,
                              void* d_out, int out_size, void* d_ws, size_t ws_size,
                              hipStream_t stream) {
    const float* x     = (const float*)d_in[0];
    const int*   ei    = (const int*)d_in[1];
    const int*   batch = (const int*)d_in[2];
    const float* w1  = (const float*)d_in[3];
    const float* as1 = (const float*)d_in[4];
    const float* ad1 = (const float*)d_in[5];
    const float* b1  = (const float*)d_in[6];
    const float* w2  = (const float*)d_in[7];
    const float* as2 = (const float*)d_in[8];
    const float* ad2 = (const float*)d_in[9];
    const float* b2  = (const float*)d_in[10];
    const float* w3  = (const float*)d_in[11];
    const float* as3 = (const float*)d_in[12];
    const float* ad3 = (const float*)d_in[13];
    const float* b3  = (const float*)d_in[14];
    const float* fc1w = (const float*)d_in[15];
    const float* fc1b = (const float*)d_in[16];
    const float* fc2w = (const float*)d_in[17];
    const float* fc2b = (const float*)d_in[18];
    float* out = (float*)d_out;

    int N  = in_sizes[0] / DIM;
    int E  = in_sizes[1] / 2;
    int EP = E + N;
    int nb = (N + 255) / 256;   // scan blocks (<= 256 for N <= 65536)

    // workspace carve (ping-pong h/as/ad buffers for the fused layers)
    char* p = (char*)d_ws;
    unsigned* hbA = (unsigned*)p; p += align256(sizeof(unsigned) * (size_t)N * (DIM / 2));
    unsigned* hbB = (unsigned*)p; p += align256(sizeof(unsigned) * (size_t)N * (DIM / 2));
    unsigned* oAb = (unsigned*)p; p += align256(sizeof(unsigned) * (size_t)N * (DIM / 2));
    float* asA  = (float*)p; p += align256(sizeof(float) * (size_t)N);
    float* adA  = (float*)p; p += align256(sizeof(float) * (size_t)N);
    float* asB  = (float*)p; p += align256(sizeof(float) * (size_t)N);
    float* adB  = (float*)p; p += align256(sizeof(float) * (size_t)N);
    int*   deg  = (int*)p;   p += align256(sizeof(int) * (size_t)N);
    int*   offs = (int*)p;   p += align256(sizeof(int) * (size_t)(N + 1));
    int*   rank = (int*)p;   p += align256(sizeof(int) * (size_t)EP);
    int2*  csr_sd = (int2*)p; p += align256(sizeof(int2) * (size_t)EP);
    int*   part = (int*)p;   p += align256(sizeof(int) * (size_t)nb);
    int*   gst  = (int*)p;   p += align256(sizeof(int) * (size_t)(GNUM + 1));

    int nfb  = (N + FUS_NPB - 1) / FUS_NPB;   // fused agg+mm blocks
    int nblk = (N + AGG_NPB - 1) / AGG_NPB;   // final gat_agg blocks
    int nbt = (N + 63) / 64;                  // mm tiles
    int epBlocks = (EP + 511) / 512;          // scatter blocks

    // CSR build (dst-grouped; layer-invariant)
    hipMemsetAsync(deg, 0, sizeof(int) * (size_t)N, stream);
    deg_rank_kernel<<<(EP + 255) / 256, 256, 0, stream>>>(ei, E, N, deg, rank);
    scan_misc<<<nb + 1, 256, 0, stream>>>(deg, part, N, nb, batch, N, gst);
    scan_down<<<nb, 256, 0, stream>>>(deg, part, offs, N);

    // layer 1 mm (+ CSR scatter overlapped)
    mm_fill<<<nbt + epBlocks, 512, 0, stream>>>(x, w1, as1, ad1, hbA, asA, adA, N, nbt,
                                                ei, rank, E, offs, csr_sd);
    // fused agg(1)+mm(2), agg(2)+mm(3)
    agg_mm<<<nfb, 512, 0, stream>>>(hbA, csr_sd, asA, adA, offs, b1, w2, as2, ad2,
                                    hbB, asB, adB, N);
    agg_mm<<<nfb, 512, 0, stream>>>(hbB, csr_sd, asB, adB, offs, b2, w3, as3, ad3,
                                    hbA, asA, adA, N);
    // final agg(3) -> bf16 rows for pooling
    gat_agg<<<nblk, 512, 0, stream>>>(hbA, csr_sd, asA, adA, offs, b3, oAb, N);

    // fused pool + head (bf16 input)
    pool_mlp<<<GNUM, 256, 0, stream>>>((const unsigned short*)oAb, gst, fc1w, fc1b, fc2w, fc2b, out);
}

// Round 8
// 248.166 us; speedup vs baseline: 1.0830x; 1.0517x over previous
//
#include <hip/hip_runtime.h>
#include <hip/hip_bf16.h>
#include <math.h>

#define DIM 64
#define GNUM 256
#define CNUM 10

// bf16x2 pack/unpack (RNE) — used only for the final layer's streamed output.
__device__ __forceinline__ unsigned bfpack(float a, float b) {
    unsigned ua = __builtin_bit_cast(unsigned, a);
    unsigned ub = __builtin_bit_cast(unsigned, b);
    ua += 0x7fffu + ((ua >> 16) & 1u);
    ub += 0x7fffu + ((ub >> 16) & 1u);
    return (ua >> 16) | (ub & 0xffff0000u);
}
__device__ __forceinline__ float bfs(unsigned short u) { return __builtin_bit_cast(float, (unsigned)u << 16); }

// ---------------- fp8 (OCP e4m3) pack/unpack via gfx950 HW cvt ----------------
// R16: h rows stored as fp8 -> 64B/row. Halves gather traffic (the measured
// ~2.2TB/s random-access floor) and shrinks hb to 3.2MB (< 4MB/XCD L2).
typedef float floatx2 __attribute__((ext_vector_type(2)));
__device__ __forceinline__ unsigned fp8x4_enc(float a, float b, float c, float d) {
    int w = __builtin_amdgcn_cvt_pk_fp8_f32(a, b, 0, false);    // bytes 0,1 (RNE, sat)
    w = __builtin_amdgcn_cvt_pk_fp8_f32(c, d, w, true);         // bytes 2,3
    return (unsigned)w;
}
__device__ __forceinline__ void fp8dec8(uint2 h, float* f) {
    floatx2 p0 = __builtin_amdgcn_cvt_pk_f32_fp8((int)h.x, false);
    floatx2 p1 = __builtin_amdgcn_cvt_pk_f32_fp8((int)h.x, true);
    floatx2 p2 = __builtin_amdgcn_cvt_pk_f32_fp8((int)h.y, false);
    floatx2 p3 = __builtin_amdgcn_cvt_pk_f32_fp8((int)h.y, true);
    f[0] = p0[0]; f[1] = p0[1]; f[2] = p1[0]; f[3] = p1[1];
    f[4] = p2[0]; f[5] = p2[1]; f[6] = p3[0]; f[7] = p3[1];
}

// ---------------- CSR build ----------------
__global__ void deg_rank_kernel(const int* __restrict__ ei, int E, int N,
                                int* __restrict__ deg, int* __restrict__ rank) {
    int i = blockIdx.x * blockDim.x + threadIdx.x;
    int EP = E + N;
    if (i >= EP) return;
    int d = (i < E) ? ei[E + i] : (i - E);   // row 1 of edge_index = dst; self loops appended
    rank[i] = atomicAdd(&deg[d], 1);
}

// scan_blocks + graph_bounds, role-split by blockIdx.
__global__ __launch_bounds__(256) void scan_misc(const int* __restrict__ deg, int* __restrict__ part, int n, int nb,
                                                 const int* __restrict__ batch, int N,
                                                 int* __restrict__ gstart) {
    int bid = blockIdx.x;
    if (bid < nb) {
        __shared__ int ws[4];
        int i = bid * 256 + threadIdx.x;
        int v = (i < n) ? deg[i] : 0;
        #pragma unroll
        for (int d = 32; d >= 1; d >>= 1) v += __shfl_xor(v, d);
        if ((threadIdx.x & 63) == 0) ws[threadIdx.x >> 6] = v;
        __syncthreads();
        if (threadIdx.x == 0) part[bid] = ws[0] + ws[1] + ws[2] + ws[3];
    } else {
        for (int g = threadIdx.x; g <= GNUM; g += 256) {
            int lo = 0, hi = N;
            while (lo < hi) { int mid = (lo + hi) >> 1; if (batch[mid] < g) lo = mid + 1; else hi = mid; }
            gstart[g] = lo;
        }
    }
}

// scan_down with the top-level scan fused (nb <= 256 for N <= 65536).
__global__ __launch_bounds__(256) void scan_down(const int* __restrict__ deg, const int* __restrict__ part,
                                                 int* __restrict__ offs, int n) {
    __shared__ int ws[4];
    __shared__ int base_s;
    int tid = threadIdx.x, lane = tid & 63, wid = tid >> 6;
    int pv = (tid < (int)blockIdx.x) ? part[tid] : 0;
    #pragma unroll
    for (int d = 32; d >= 1; d >>= 1) pv += __shfl_xor(pv, d);
    if (lane == 0) ws[wid] = pv;
    __syncthreads();
    if (tid == 0) base_s = ws[0] + ws[1] + ws[2] + ws[3];
    __syncthreads();
    int i = blockIdx.x * 256 + tid;
    int v = (i < n) ? deg[i] : 0;
    int x = v;
    #pragma unroll
    for (int d = 1; d < 64; d <<= 1) { int t = __shfl_up(x, d); if (lane >= d) x += t; }
    if (lane == 63) ws[wid] = x;
    __syncthreads();
    int add = base_s;
    for (int w = 0; w < wid; ++w) add += ws[w];
    if (i < n) offs[i] = add + x - v;
    if (i == n - 1) offs[n] = add + x;
}

// ---------------- 4-wide fp8 gather (R12 width, fp8 rows) ----------------
// 8-lane group per node; lane fg reads uint2 (8 fp8) at row*64B + fg*8B ->
// one coalesced 64B transaction per edge. HW cvt decode (4 ops/edge/lane).
__device__ __forceinline__ void gat_gather4(const unsigned* __restrict__ hb,
                                            const int2* __restrict__ lsw,
                                            int ls, int deg, int fg,
                                            float& a0, float& a1, float& a2, float& a3,
                                            float& a4, float& a5, float& a6, float& a7,
                                            float& sw) {
    for (int eb = 0; eb < deg; eb += 4) {
        int t = ls + eb;
        int2 eA = lsw[t], eB = lsw[t + 1], eC = lsw[t + 2], eD = lsw[t + 3];
        float wA = __builtin_bit_cast(float, eA.y);
        float wB = (eb + 1 < deg) ? __builtin_bit_cast(float, eB.y) : 0.f;
        float wC = (eb + 2 < deg) ? __builtin_bit_cast(float, eC.y) : 0.f;
        float wD = (eb + 3 < deg) ? __builtin_bit_cast(float, eD.y) : 0.f;
        const uint2 hA = *(const uint2*)(hb + ((size_t)eA.x << 4) + (fg << 1));
        const uint2 hB = *(const uint2*)(hb + ((size_t)eB.x << 4) + (fg << 1));
        const uint2 hC = *(const uint2*)(hb + ((size_t)eC.x << 4) + (fg << 1));
        const uint2 hD = *(const uint2*)(hb + ((size_t)eD.x << 4) + (fg << 1));
        float fA[8], fB[8], fC[8], fD[8];
        fp8dec8(hA, fA); fp8dec8(hB, fB); fp8dec8(hC, fC); fp8dec8(hD, fD);
        sw += wA + wB + wC + wD;
        a0 += wA * fA[0] + wB * fB[0] + wC * fC[0] + wD * fD[0];
        a1 += wA * fA[1] + wB * fB[1] + wC * fC[1] + wD * fD[1];
        a2 += wA * fA[2] + wB * fB[2] + wC * fC[2] + wD * fD[2];
        a3 += wA * fA[3] + wB * fB[3] + wC * fC[3] + wD * fD[3];
        a4 += wA * fA[4] + wB * fB[4] + wC * fC[4] + wD * fD[4];
        a5 += wA * fA[5] + wB * fB[5] + wC * fC[5] + wD * fD[5];
        a6 += wA * fA[6] + wB * fB[6] + wC * fC[6] + wD * fD[6];
        a7 += wA * fA[7] + wB * fB[7] + wC * fC[7] + wD * fD[7];
    }
}

// ---------------- 512-thread 64x64 mm pieces ----------------
#define XSTR 68
// hbn rows are fp8: 16 unsigned words (64B) per node.
__device__ __forceinline__ void mm_core_512(const float* __restrict__ xT, const float* __restrict__ Ws,
                                            const float* __restrict__ a_s, const float* __restrict__ a_d,
                                            unsigned* __restrict__ hbn, float* __restrict__ asn,
                                            float* __restrict__ adn, int base, int N) {
    int tid = threadIdx.x;
    int tx = tid & 15, ty = tid >> 4;          // ty 0..31
    int c0 = tx << 2, r0 = ty << 1;
    float acc[2][4] = {{0.f}};
    #pragma unroll 8
    for (int k = 0; k < DIM; ++k) {
        float2 xv = *(const float2*)(xT + k * XSTR + r0);
        float4 wv = *(const float4*)(Ws + k * DIM + c0);
        acc[0][0] += xv.x * wv.x; acc[0][1] += xv.x * wv.y; acc[0][2] += xv.x * wv.z; acc[0][3] += xv.x * wv.w;
        acc[1][0] += xv.y * wv.x; acc[1][1] += xv.y * wv.y; acc[1][2] += xv.y * wv.z; acc[1][3] += xv.y * wv.w;
    }
    float4 av = *(const float4*)(a_s + c0);
    float4 dv = *(const float4*)(a_d + c0);
    #pragma unroll
    for (int ri = 0; ri < 2; ++ri) {
        int grow = base + r0 + ri;
        float s1 = acc[ri][0] * av.x + acc[ri][1] * av.y + acc[ri][2] * av.z + acc[ri][3] * av.w;
        float s2 = acc[ri][0] * dv.x + acc[ri][1] * dv.y + acc[ri][2] * dv.z + acc[ri][3] * dv.w;
        #pragma unroll
        for (int d = 1; d <= 8; d <<= 1) { s1 += __shfl_xor(s1, d); s2 += __shfl_xor(s2, d); }
        if (grow < N) {
            hbn[((size_t)grow << 4) + tx] = fp8x4_enc(acc[ri][0], acc[ri][1], acc[ri][2], acc[ri][3]);
            if (tx == 0) { asn[grow] = s1; adn[grow] = s2; }
        }
    }
}

// layer-1 mm (f32 input, 512 threads) + atomic-free CSR scatter, role-split.
__global__ __launch_bounds__(512) void mm_fill(const float* __restrict__ in, const float* __restrict__ W,
                                               const float* __restrict__ a_s, const float* __restrict__ a_d,
                                               unsigned* __restrict__ hb, float* __restrict__ as_,
                                               float* __restrict__ ad_, int N, int nbt,
                                               const int* __restrict__ ei, const int* __restrict__ rank, int E,
                                               const int* __restrict__ offs, int2* __restrict__ csr_sd) {
    int bid = blockIdx.x;
    if (bid < nbt) {
        __shared__ float Ws[DIM * DIM];
        __shared__ float xT[XSTR * DIM];
        int tid = threadIdx.x;
        int base = bid * 64;

        const float4* W4 = (const float4*)W;
        float4* Ws4 = (float4*)Ws;
        Ws4[tid] = W4[tid];
        Ws4[tid + 512] = W4[tid + 512];

        {
            int row = tid >> 3;
            int kb = (tid & 7) << 3;
            int grow = base + row;
            int crow = grow < N ? grow : N - 1;
            const float4* xr = (const float4*)(in + ((size_t)crow << 6) + kb);
            float4 v0 = xr[0], v1 = xr[1];
            xT[(kb + 0) * XSTR + row] = v0.x;  xT[(kb + 1) * XSTR + row] = v0.y;
            xT[(kb + 2) * XSTR + row] = v0.z;  xT[(kb + 3) * XSTR + row] = v0.w;
            xT[(kb + 4) * XSTR + row] = v1.x;  xT[(kb + 5) * XSTR + row] = v1.y;
            xT[(kb + 6) * XSTR + row] = v1.z;  xT[(kb + 7) * XSTR + row] = v1.w;
        }
        __syncthreads();
        mm_core_512(xT, Ws, a_s, a_d, hb, as_, ad_, base, N);
    } else {
        int i = (bid - nbt) * 512 + threadIdx.x;
        int EP = E + N;
        if (i >= EP) return;
        int s, d;
        if (i < E) { s = ei[i]; d = ei[E + i]; } else { s = i - E; d = i - E; }
        csr_sd[offs[d] + rank[i]] = make_int2(s, d);
    }
}

// ---------------- fused agg(layer k) + mm(layer k+1), 512 threads ----------------
#define FUS_NPB 64
#define FUS_CAP 2560
__global__ __launch_bounds__(512) void agg_mm(const unsigned* __restrict__ hbp,
                                              const int2* __restrict__ csr_sd,
                                              const float* __restrict__ asp,
                                              const float* __restrict__ adp,
                                              const int* __restrict__ offs,
                                              const float* __restrict__ bias,
                                              const float* __restrict__ W,
                                              const float* __restrict__ a_s,
                                              const float* __restrict__ a_d,
                                              unsigned* __restrict__ hbn,
                                              float* __restrict__ asn,
                                              float* __restrict__ adn, int N) {
    __shared__ int soffs[FUS_NPB + 1];
    __shared__ float adl[FUS_NPB];
    __shared__ int2 lsw[FUS_CAP + 4];          // 20 KB; reused as Ws (16 KB) in mm phase
    __shared__ float xT[XSTR * DIM];           // 17.4 KB
    float* Ws = (float*)lsw;

    int tid = threadIdx.x;
    int base = blockIdx.x * FUS_NPB;
    if (tid <= FUS_NPB) {
        int n = base + tid;
        soffs[tid] = offs[n < N ? n : N];
    }
    if (tid < FUS_NPB) {
        int n = base + tid;
        adl[tid] = (n < N) ? adp[n] : 0.f;
    }
    __syncthreads();
    int estart = soffs[0];
    int nE = soffs[FUS_NPB] - estart;
    bool inLds = (nE <= FUS_CAP);
    if (inLds) {
        for (int i = tid; i < nE; i += 512) {
            int2 sd = csr_sd[estart + i];
            float e = asp[sd.x] + adl[sd.y - base];
            e = (e > 0.f) ? e : 0.2f * e;
            lsw[i] = make_int2(sd.x, __builtin_bit_cast(int, expf(e)));
        }
        if (tid < 4) lsw[nE + tid] = make_int2(0, 0);
    }
    __syncthreads();

    int li = tid >> 3, fg = tid & 7;           // one 8-lane group per node
    int node = base + li;
    int ls = soffs[li] - estart;
    int deg = soffs[li + 1] - soffs[li];

    float a0 = 0.f, a1 = 0.f, a2 = 0.f, a3 = 0.f;
    float a4 = 0.f, a5 = 0.f, a6 = 0.f, a7 = 0.f, sw = 0.f;
    if (inLds) {
        gat_gather4(hbp, lsw, ls, deg, fg, a0, a1, a2, a3, a4, a5, a6, a7, sw);
    } else {
        // cold fallback: same math from global, fully clamped/masked
        float adi = adl[li];
        for (int eb = 0; eb < deg; eb += 4) {
            int t = estart + ls + eb;
            float wv[4]; int sv[4];
            #pragma unroll
            for (int k = 0; k < 4; ++k) {
                int2 sd = (eb + k < deg) ? csr_sd[t + k] : make_int2(0, 0);
                int s = sd.x; s = s < 0 ? 0 : (s >= N ? N - 1 : s);
                float e = asp[s] + adi;
                e = (e > 0.f) ? e : 0.2f * e;
                wv[k] = (eb + k < deg) ? expf(e) : 0.f;
                sv[k] = s;
            }
            #pragma unroll
            for (int k = 0; k < 4; ++k) {
                const uint2 hv = *(const uint2*)(hbp + ((size_t)sv[k] << 4) + (fg << 1));
                float fv[8];
                fp8dec8(hv, fv);
                sw += wv[k];
                a0 += wv[k] * fv[0]; a1 += wv[k] * fv[1];
                a2 += wv[k] * fv[2]; a3 += wv[k] * fv[3];
                a4 += wv[k] * fv[4]; a5 += wv[k] * fv[5];
                a6 += wv[k] * fv[6]; a7 += wv[k] * fv[7];
            }
        }
    }

    float inv = 1.f / (sw + 1e-16f);
    const float4 b0 = *(const float4*)(bias + (fg << 3));
    const float4 b1 = *(const float4*)(bias + (fg << 3) + 4);
    float o0 = a0 * inv + b0.x, o1 = a1 * inv + b0.y, o2 = a2 * inv + b0.z, o3 = a3 * inv + b0.w;
    float o4 = a4 * inv + b1.x, o5 = a5 * inv + b1.y, o6 = a6 * inv + b1.z, o7 = a7 * inv + b1.w;
    float n2 = o0 * o0 + o1 * o1 + o2 * o2 + o3 * o3 + o4 * o4 + o5 * o5 + o6 * o6 + o7 * o7;
    #pragma unroll
    for (int d = 1; d <= 4; d <<= 1) n2 += __shfl_xor(n2, d);   // across the 8 fg lanes
    float innrm = 1.f / fmaxf(sqrtf(n2), 1e-12f);
    if (node >= N) innrm = 0.f;                // keep xT clean for pad rows
    int kb = fg << 3;
    xT[(kb + 0) * XSTR + li] = fmaxf(o0 * innrm, 0.f);
    xT[(kb + 1) * XSTR + li] = fmaxf(o1 * innrm, 0.f);
    xT[(kb + 2) * XSTR + li] = fmaxf(o2 * innrm, 0.f);
    xT[(kb + 3) * XSTR + li] = fmaxf(o3 * innrm, 0.f);
    xT[(kb + 4) * XSTR + li] = fmaxf(o4 * innrm, 0.f);
    xT[(kb + 5) * XSTR + li] = fmaxf(o5 * innrm, 0.f);
    xT[(kb + 6) * XSTR + li] = fmaxf(o6 * innrm, 0.f);
    xT[(kb + 7) * XSTR + li] = fmaxf(o7 * innrm, 0.f);
    __syncthreads();                            // agg done; lsw region free

    const float4* W4 = (const float4*)W;
    float4* Ws4 = (float4*)Ws;
    Ws4[tid] = W4[tid];
    Ws4[tid + 512] = W4[tid + 512];
    __syncthreads();
    mm_core_512(xT, Ws, a_s, a_d, hbn, asn, adn, base, N);
}

// ---------------- per-node softmax-aggregate (final layer, 512 threads) ----------------
// Reads fp8 hb, writes bf16 rows (streamed, pool accuracy) to outb.
#define AGG_NPB 64
#define AGG_CAP 2560
__global__ __launch_bounds__(512) void gat_agg(const unsigned* __restrict__ hb,
                                               const int2* __restrict__ csr_sd,
                                               const float* __restrict__ as_,
                                               const float* __restrict__ ad_,
                                               const int* __restrict__ offs,
                                               const float* __restrict__ bias,
                                               unsigned* __restrict__ outb, int N) {
    __shared__ int soffs[AGG_NPB + 1];
    __shared__ float adl[AGG_NPB];
    __shared__ int2 lsw[AGG_CAP + 4];
    int tid = threadIdx.x;
    int base = blockIdx.x * AGG_NPB;
    if (tid <= AGG_NPB) {
        int n = base + tid;
        soffs[tid] = offs[n < N ? n : N];
    }
    if (tid < AGG_NPB) {
        int n = base + tid;
        adl[tid] = (n < N) ? ad_[n] : 0.f;
    }
    __syncthreads();
    int estart = soffs[0];
    int nE = soffs[AGG_NPB] - estart;
    bool inLds = (nE <= AGG_CAP);
    if (inLds) {
        for (int i = tid; i < nE; i += 512) {
            int2 sd = csr_sd[estart + i];
            float e = as_[sd.x] + adl[sd.y - base];
            e = (e > 0.f) ? e : 0.2f * e;
            lsw[i] = make_int2(sd.x, __builtin_bit_cast(int, expf(e)));
        }
        if (tid < 4) lsw[nE + tid] = make_int2(0, 0);
    }
    __syncthreads();

    int li = tid >> 3, fg = tid & 7;
    int node = base + li;
    int ls = soffs[li] - estart;
    int deg = soffs[li + 1] - soffs[li];

    float a0 = 0.f, a1 = 0.f, a2 = 0.f, a3 = 0.f;
    float a4 = 0.f, a5 = 0.f, a6 = 0.f, a7 = 0.f, sw = 0.f;
    if (inLds) {
        gat_gather4(hb, lsw, ls, deg, fg, a0, a1, a2, a3, a4, a5, a6, a7, sw);
    } else {
        float adi = (node < N) ? ad_[node] : 0.f;
        for (int eb = 0; eb < deg; eb += 4) {
            int t = estart + ls + eb;
            float wv[4]; int sv[4];
            #pragma unroll
            for (int k = 0; k < 4; ++k) {
                int2 sd = (eb + k < deg) ? csr_sd[t + k] : make_int2(0, 0);
                int s = sd.x; s = s < 0 ? 0 : (s >= N ? N - 1 : s);
                float e = as_[s] + adi;
                e = (e > 0.f) ? e : 0.2f * e;
                wv[k] = (eb + k < deg) ? expf(e) : 0.f;
                sv[k] = s;
            }
            #pragma unroll
            for (int k = 0; k < 4; ++k) {
                const uint2 hv = *(const uint2*)(hb + ((size_t)sv[k] << 4) + (fg << 1));
                float fv[8];
                fp8dec8(hv, fv);
                sw += wv[k];
                a0 += wv[k] * fv[0]; a1 += wv[k] * fv[1];
                a2 += wv[k] * fv[2]; a3 += wv[k] * fv[3];
                a4 += wv[k] * fv[4]; a5 += wv[k] * fv[5];
                a6 += wv[k] * fv[6]; a7 += wv[k] * fv[7];
            }
        }
    }

    float inv = 1.f / (sw + 1e-16f);
    const float4 b0 = *(const float4*)(bias + (fg << 3));
    const float4 b1 = *(const float4*)(bias + (fg << 3) + 4);
    float o0 = a0 * inv + b0.x, o1 = a1 * inv + b0.y, o2 = a2 * inv + b0.z, o3 = a3 * inv + b0.w;
    float o4 = a4 * inv + b1.x, o5 = a5 * inv + b1.y, o6 = a6 * inv + b1.z, o7 = a7 * inv + b1.w;
    float n2 = o0 * o0 + o1 * o1 + o2 * o2 + o3 * o3 + o4 * o4 + o5 * o5 + o6 * o6 + o7 * o7;
    #pragma unroll
    for (int d = 1; d <= 4; d <<= 1) n2 += __shfl_xor(n2, d);   // across the 8 fg lanes
    float innrm = 1.f / fmaxf(sqrtf(n2), 1e-12f);
    if (node < N) {
        uint4 o;
        o.x = bfpack(fmaxf(o0 * innrm, 0.f), fmaxf(o1 * innrm, 0.f));
        o.y = bfpack(fmaxf(o2 * innrm, 0.f), fmaxf(o3 * innrm, 0.f));
        o.z = bfpack(fmaxf(o4 * innrm, 0.f), fmaxf(o5 * innrm, 0.f));
        o.w = bfpack(fmaxf(o6 * innrm, 0.f), fmaxf(o7 * innrm, 0.f));
        *(uint4*)(outb + ((size_t)node << 5) + (fg << 2)) = o;
    }
}

// ---------------- fused global_add_pool + MLP + log_softmax ----------------
__global__ __launch_bounds__(256) void pool_mlp(const unsigned short* __restrict__ hb, const int* __restrict__ gstart,
                                                const float* __restrict__ fc1w, const float* __restrict__ fc1b,
                                                const float* __restrict__ fc2w, const float* __restrict__ fc2b,
                                                float* __restrict__ out) {
    __shared__ float W1[DIM * DIM];
    __shared__ float red[4 * DIM];
    __shared__ float tbuf[DIM];
    __shared__ float obuf[CNUM];
    int tid = threadIdx.x, lane = tid & 63, wv = tid >> 6;
    int gid = blockIdx.x;

    const float4* W4 = (const float4*)fc1w;
    float4* W1s = (float4*)W1;
    #pragma unroll
    for (int i = 0; i < 4; ++i) W1s[tid + 256 * i] = W4[tid + 256 * i];

    int s = gstart[gid], e = gstart[gid + 1];
    float acc = 0.f;
    for (int i = s + wv; i < e; i += 4) acc += bfs(hb[((size_t)i << 6) + lane]);
    red[wv * DIM + lane] = acc;
    __syncthreads();

    if (wv == 0) {
        float g = red[lane] + red[DIM + lane] + red[2 * DIM + lane] + red[3 * DIM + lane];
        float t = fc1b[lane];
        #pragma unroll
        for (int k = 0; k < DIM; ++k) t += __shfl(g, k) * W1[k * DIM + lane];
        t = fmaxf(t, 0.f);
        tbuf[lane] = t;
        float o = 0.f;
        if (lane < CNUM) {
            o = fc2b[lane];
            #pragma unroll
            for (int k = 0; k < DIM; ++k) o += tbuf[k] * fc2w[k * CNUM + lane];
            obuf[lane] = o;
        }
        if (lane < CNUM) {
            float mx = obuf[0];
            #pragma unroll
            for (int k = 1; k < CNUM; ++k) mx = fmaxf(mx, obuf[k]);
            float ssum = 0.f;
            #pragma unroll
            for (int k = 0; k < CNUM; ++k) ssum += expf(obuf[k] - mx);
            out[gid * CNUM + lane] = o - mx - logf(ssum);
        }
    }
}

// ---------------- launch ----------------
static inline size_t align256(size_t x) { return (x + 255) & ~size_t(255); }

extern "C" void kernel_launch(void* const* d_in, const int* in_sizes, int n_in,
                              void* d_out, int out_size, void* d_ws, size_t ws_size,
                              hipStream_t stream) {
    const float* x     = (const float*)d_in[0];
    const int*   ei    = (const int*)d_in[1];
    const int*   batch = (const int*)d_in[2];
    const float* w1  = (const float*)d_in[3];
    const float* as1 = (const float*)d_in[4];
    const float* ad1 = (const float*)d_in[5];
    const float* b1  = (const float*)d_in[6];
    const float* w2  = (const float*)d_in[7];
    const float* as2 = (const float*)d_in[8];
    const float* ad2 = (const float*)d_in[9];
    const float* b2  = (const float*)d_in[10];
    const float* w3  = (const float*)d_in[11];
    const float* as3 = (const float*)d_in[12];
    const float* ad3 = (const float*)d_in[13];
    const float* b3  = (const float*)d_in[14];
    const float* fc1w = (const float*)d_in[15];
    const float* fc1b = (const float*)d_in[16];
    const float* fc2w = (const float*)d_in[17];
    const float* fc2b = (const float*)d_in[18];
    float* out = (float*)d_out;

    int N  = in_sizes[0] / DIM;
    int E  = in_sizes[1] / 2;
    int EP = E + N;
    int nb = (N + 255) / 256;   // scan blocks (<= 256 for N <= 65536)

    // workspace carve (fp8 h ping-pong: 16 words/row; bf16 final rows: 32 words)
    char* p = (char*)d_ws;
    unsigned* hbA = (unsigned*)p; p += align256(sizeof(unsigned) * (size_t)N * (DIM / 4));
    unsigned* hbB = (unsigned*)p; p += align256(sizeof(unsigned) * (size_t)N * (DIM / 4));
    unsigned* oAb = (unsigned*)p; p += align256(sizeof(unsigned) * (size_t)N * (DIM / 2));
    float* asA  = (float*)p; p += align256(sizeof(float) * (size_t)N);
    float* adA  = (float*)p; p += align256(sizeof(float) * (size_t)N);
    float* asB  = (float*)p; p += align256(sizeof(float) * (size_t)N);
    float* adB  = (float*)p; p += align256(sizeof(float) * (size_t)N);
    int*   deg  = (int*)p;   p += align256(sizeof(int) * (size_t)N);
    int*   offs = (int*)p;   p += align256(sizeof(int) * (size_t)(N + 1));
    int*   rank = (int*)p;   p += align256(sizeof(int) * (size_t)EP);
    int2*  csr_sd = (int2*)p; p += align256(sizeof(int2) * (size_t)EP);
    int*   part = (int*)p;   p += align256(sizeof(int) * (size_t)nb);
    int*   gst  = (int*)p;   p += align256(sizeof(int) * (size_t)(GNUM + 1));

    int nfb  = (N + FUS_NPB - 1) / FUS_NPB;   // fused agg+mm blocks
    int nblk = (N + AGG_NPB - 1) / AGG_NPB;   // final gat_agg blocks
    int nbt = (N + 63) / 64;                  // mm tiles
    int epBlocks = (EP + 511) / 512;          // scatter blocks

    // CSR build (dst-grouped; layer-invariant)
    hipMemsetAsync(deg, 0, sizeof(int) * (size_t)N, stream);
    deg_rank_kernel<<<(EP + 255) / 256, 256, 0, stream>>>(ei, E, N, deg, rank);
    scan_misc<<<nb + 1, 256, 0, stream>>>(deg, part, N, nb, batch, N, gst);
    scan_down<<<nb, 256, 0, stream>>>(deg, part, offs, N);

    // layer 1 mm (+ CSR scatter overlapped)
    mm_fill<<<nbt + epBlocks, 512, 0, stream>>>(x, w1, as1, ad1, hbA, asA, adA, N, nbt,
                                                ei, rank, E, offs, csr_sd);
    // fused agg(1)+mm(2), agg(2)+mm(3)
    agg_mm<<<nfb, 512, 0, stream>>>(hbA, csr_sd, asA, adA, offs, b1, w2, as2, ad2,
                                    hbB, asB, adB, N);
    agg_mm<<<nfb, 512, 0, stream>>>(hbB, csr_sd, asB, adB, offs, b2, w3, as3, ad3,
                                    hbA, asA, adA, N);
    // final agg(3) -> bf16 rows for pooling
    gat_agg<<<nblk, 512, 0, stream>>>(hbA, csr_sd, asA, adA, offs, b3, oAb, N);

    // fused pool + head (bf16 input)
    pool_mlp<<<GNUM, 256, 0, stream>>>((const unsigned short*)oAb, gst, fc1w, fc1b, fc2w, fc2b, out);
}